// Round 9
// baseline (322.945 us; speedup 1.0000x reference)
//
#include <hip/hip_runtime.h>

#define KNN_INF 3.0e38f

// ---- pack sparse points into float4 (x,y,z,|p|^2), all stages, one launch ----
struct PackAll {
    const float* src[4];   // [B*N2*3]
    float4* dst[4];        // [B*N2]
    int c1, c2, c3;
};
__global__ void pack_kernel(PackAll P, int total) {
    int t = blockIdx.x * 256 + threadIdx.x;
    if (t >= total) return;
    int s = (t >= P.c1) + (t >= P.c2) + (t >= P.c3);
    int start = (s == 0) ? 0 : (s == 1) ? P.c1 : (s == 2) ? P.c2 : P.c3;
    int i = t - start;
    const float* q = P.src[s] + (size_t)i * 3;
    float x = q[0], y = q[1], z = q[2];
    P.dst[s][i] = make_float4(x, y, z, x * x + y * y + z * z);
}

// ---- stage-3 kNN: Q=4 queries/thread, LDS-staged candidates ----
__global__ __launch_bounds__(256) void knn_s3_kernel(
    const float* __restrict__ p1,     // [B,N1,3]
    const float4* __restrict__ c4,    // [B,N2]
    float* __restrict__ pd, int* __restrict__ pi,  // [B,N1,nchunk,3]
    int N1, int N2, int nchunk) {
    __shared__ float4 sm4[256];
    int b = blockIdx.y;
    int z = blockIdx.z;
    int m0 = z * 256;
    sm4[threadIdx.x] = c4[(size_t)b * N2 + m0 + threadIdx.x];
    __syncthreads();
    int nb = blockIdx.x * 1024 + threadIdx.x;
    float px[4], py[4], pz[4], s1[4];
    float t0[4], t1[4], t2[4];
    int i0[4], i1[4], i2[4];
#pragma unroll
    for (int j = 0; j < 4; ++j) {
        int n = nb + j * 256;
        const float* pp = p1 + ((size_t)b * N1 + n) * 3;
        px[j] = pp[0]; py[j] = pp[1]; pz[j] = pp[2];
        s1[j] = px[j] * px[j] + py[j] * py[j] + pz[j] * pz[j];
        t0[j] = KNN_INF; t1[j] = KNN_INF; t2[j] = KNN_INF;
        i0[j] = 0; i1[j] = 0; i2[j] = 0;
    }
    for (int m = 0; m < 256; ++m) {
        float4 q = sm4[m];
#pragma unroll
        for (int j = 0; j < 4; ++j) {
            float dot = px[j] * q.x + py[j] * q.y + pz[j] * q.z;
            float t = fmaf(-2.0f, dot, q.w);
            if (t < t2[j]) {
                if (t < t1[j]) {
                    t2[j] = t1[j]; i2[j] = i1[j];
                    if (t < t0[j]) { t1[j] = t0[j]; i1[j] = i0[j]; t0[j] = t; i0[j] = m; }
                    else           { t1[j] = t;  i1[j] = m; }
                } else { t2[j] = t; i2[j] = m; }
            }
        }
    }
#pragma unroll
    for (int j = 0; j < 4; ++j) {
        int n = nb + j * 256;
        size_t base = (((size_t)b * N1 + n) * nchunk + z) * 3;
        pd[base + 0] = s1[j] + t0[j]; pd[base + 1] = s1[j] + t1[j]; pd[base + 2] = s1[j] + t2[j];
        pi[base + 0] = m0 + i0[j]; pi[base + 1] = m0 + i1[j]; pi[base + 2] = m0 + i2[j];
    }
}

// ---- stages 0..2 chunked kNN via wave-uniform loads (r8 path, small work) ----
struct KnnAll3 {
    const float* p1[3];
    const float4* c4[3];
    float* pd[3]; int* pi[3];
    int N1[3], N2[3], chunk[3], nchunk[3], nbx[3];
    int bs1, bs2;
};
__global__ __launch_bounds__(256) void knn_small_kernel(KnnAll3 P) {
    int bid = blockIdx.x;
    int s = (bid >= P.bs1) + (bid >= P.bs2);
    int start = (s == 0) ? 0 : (s == 1) ? P.bs1 : P.bs2;
    int local = bid - start;
    int nbx = P.nbx[s];
    int bx = local % nbx;
    int rest = local / nbx;
    int b = rest & 7;
    int z = rest >> 3;
    int N1 = P.N1[s], N2 = P.N2[s], chunk = P.chunk[s], nchunk = P.nchunk[s];
    int m0 = z * chunk;
    const float4* __restrict__ cb = P.c4[s] + (size_t)b * N2 + m0;
    int n = bx * 256 + threadIdx.x;
    if (n >= N1) return;
    const float* p1b = P.p1[s] + ((size_t)b * N1 + n) * 3;
    float px = p1b[0], py = p1b[1], pz = p1b[2];
    float s1 = px * px + py * py + pz * pz;
    float t0 = KNN_INF, t1 = KNN_INF, t2 = KNN_INF;
    int i0 = 0, i1 = 0, i2 = 0;
    for (int m = 0; m < chunk; ++m) {
        float4 q = cb[m];
        float dot = px * q.x + py * q.y + pz * q.z;
        float t = fmaf(-2.0f, dot, q.w);
        if (t < t2) {
            if (t < t1) {
                t2 = t1; i2 = i1;
                if (t < t0) { t1 = t0; i1 = i0; t0 = t; i0 = m; }
                else        { t1 = t;  i1 = m; }
            } else { t2 = t; i2 = m; }
        }
    }
    size_t base = (((size_t)b * N1 + n) * nchunk + z) * 3;
    float* pd = P.pd[s]; int* pi = P.pi[s];
    pd[base + 0] = s1 + t0; pd[base + 1] = s1 + t1; pd[base + 2] = s1 + t2;
    pi[base + 0] = m0 + i0; pi[base + 1] = m0 + i1; pi[base + 2] = m0 + i2;
}

// ---- merge partial top-3s (global-index order) + weights, all stages ----
struct MergeAll4 {
    const float* pd[4]; const int* pi[4];
    int* idx[4]; float* w[4];
    int nchunk[4];
    int ts1, ts2, ts3;
};
__global__ void knn_merge_all_kernel(MergeAll4 P, int total) {
    int t = blockIdx.x * blockDim.x + threadIdx.x;
    if (t >= total) return;
    int s = (t >= P.ts1) + (t >= P.ts2) + (t >= P.ts3);
    int start = (s == 0) ? 0 : (s == 1) ? P.ts1 : (s == 2) ? P.ts2 : P.ts3;
    int lt = t - start;
    int nchunk = P.nchunk[s];
    float d0 = KNN_INF, d1 = KNN_INF, d2 = KNN_INF;
    int i0 = 0, i1 = 0, i2 = 0;
    const float* pd = P.pd[s]; const int* pi = P.pi[s];
    size_t base = (size_t)lt * nchunk * 3;
    for (int c = 0; c < nchunk * 3; ++c) {
        float d = pd[base + c];
        int   i = pi[base + c];
        if (d < d2) {
            if (d < d1) {
                d2 = d1; i2 = i1;
                if (d < d0) { d1 = d0; i1 = i0; d0 = d; i0 = i; }
                else        { d1 = d;  i1 = i; }
            } else { d2 = d; i2 = i; }
        }
    }
    float dd0 = fmaxf(d0, 0.0f), dd1 = fmaxf(d1, 0.0f), dd2 = fmaxf(d2, 0.0f);
    float w0 = 1.0f / (dd0 + 1e-8f);
    float w1 = 1.0f / (dd1 + 1e-8f);
    float w2 = 1.0f / (dd2 + 1e-8f);
    float wsum = w0 + w1 + w2;
    w0 /= wsum; w1 /= wsum; w2 /= wsum;
    size_t ob = (size_t)lt * 3;
    P.idx[s][ob + 0] = i0; P.idx[s][ob + 1] = i1; P.idx[s][ob + 2] = i2;
    P.w[s][ob + 0] = w0; P.w[s][ob + 1] = w1; P.w[s][ob + 2] = w2;
}

// ================== conv kernels (r5-proven) ==================
#define TO 32
#define TN 64
#define BK 16
template<bool PARTIAL>
__global__ __launch_bounds__(256) void conv_a_fused_kernel(
    const float* __restrict__ f1, const float* __restrict__ x2,
    const int* __restrict__ idxS, const float* __restrict__ wS,
    const float* __restrict__ W, const float* __restrict__ g, const float* __restrict__ bv,
    float* __restrict__ Y,
    int C1, int C2, int N, int N2, int Cout, int chunk) {
    __shared__ float Ws[BK][TO];
    __shared__ float Xs[BK][TN];
    int Cin = C1 + C2;
    int zb = blockIdx.z;
    int b = zb & 7;
    int split = zb >> 3;
    int kBase = split * chunk;
    int oBase = blockIdx.y * TO;
    int nBase = blockIdx.x * TN;
    int tid = threadIdx.x;
    int tx = tid & 15;
    int ty = tid >> 4;
    int nn = tid & 63;
    int kk0 = tid >> 6;
    int n = nBase + nn;
    size_t gb = ((size_t)b * N + n) * 3;
    int j0 = idxS[gb + 0], j1 = idxS[gb + 1], j2 = idxS[gb + 2];
    float w0g = wS[gb + 0], w1g = wS[gb + 1], w2g = wS[gb + 2];
    const float* f1b = f1 + (size_t)b * C1 * N;
    const float* x2b = x2 + (size_t)b * C2 * N2;
    float acc[2][4] = {{0.f, 0.f, 0.f, 0.f}, {0.f, 0.f, 0.f, 0.f}};
    for (int k0 = kBase; k0 < kBase + chunk; k0 += BK) {
        for (int t = tid; t < TO * BK; t += 256) {
            int o = t / BK, kk = t % BK;
            Ws[kk][o] = W[(size_t)(oBase + o) * Cin + k0 + kk];
        }
#pragma unroll
        for (int i = 0; i < 4; ++i) {
            int kk = kk0 + i * 4;
            int k = k0 + kk;
            float v;
            if (k < C1) {
                v = f1b[(size_t)k * N + n];
            } else {
                const float* r = x2b + (size_t)(k - C1) * N2;
                v = r[j0] * w0g + r[j1] * w1g + r[j2] * w2g;
            }
            Xs[kk][nn] = v;
        }
        __syncthreads();
#pragma unroll
        for (int kk = 0; kk < BK; ++kk) {
            float w0 = Ws[kk][ty * 2 + 0];
            float w1 = Ws[kk][ty * 2 + 1];
            float4 xv = *reinterpret_cast<const float4*>(&Xs[kk][tx * 4]);
            acc[0][0] = fmaf(w0, xv.x, acc[0][0]);
            acc[0][1] = fmaf(w0, xv.y, acc[0][1]);
            acc[0][2] = fmaf(w0, xv.z, acc[0][2]);
            acc[0][3] = fmaf(w0, xv.w, acc[0][3]);
            acc[1][0] = fmaf(w1, xv.x, acc[1][0]);
            acc[1][1] = fmaf(w1, xv.y, acc[1][1]);
            acc[1][2] = fmaf(w1, xv.z, acc[1][2]);
            acc[1][3] = fmaf(w1, xv.w, acc[1][3]);
        }
        __syncthreads();
    }
#pragma unroll
    for (int r = 0; r < 2; ++r) {
        int o = oBase + ty * 2 + r;
        float4 st;
        if (PARTIAL) {
            st.x = acc[r][0]; st.y = acc[r][1]; st.z = acc[r][2]; st.w = acc[r][3];
            *reinterpret_cast<float4*>(&Y[((size_t)zb * Cout + o) * N + nBase + tx * 4]) = st;
        } else {
            float gg = g[o], bb = bv[o];
            st.x = fmaxf(fmaf(acc[r][0], gg, bb), 0.0f);
            st.y = fmaxf(fmaf(acc[r][1], gg, bb), 0.0f);
            st.z = fmaxf(fmaf(acc[r][2], gg, bb), 0.0f);
            st.w = fmaxf(fmaf(acc[r][3], gg, bb), 0.0f);
            *reinterpret_cast<float4*>(&Y[((size_t)b * Cout + o) * N + nBase + tx * 4]) = st;
        }
    }
}

template<bool PARTIAL>
__global__ __launch_bounds__(256) void conv_gemm_kernel(
    const float* __restrict__ X, const float* __restrict__ W,
    const float* __restrict__ g, const float* __restrict__ bv,
    float* __restrict__ Y, int Cin, int Cout, int N, int chunk) {
    __shared__ float Ws[BK][TO];
    __shared__ float Xs[BK][TN];
    int zb = blockIdx.z;
    int b = zb & 7;
    int split = zb >> 3;
    int kBase = split * chunk;
    int oBase = blockIdx.y * TO;
    int nBase = blockIdx.x * TN;
    int tid = threadIdx.x;
    int tx = tid & 15;
    int ty = tid >> 4;
    float acc[2][4] = {{0.f, 0.f, 0.f, 0.f}, {0.f, 0.f, 0.f, 0.f}};
    const float* Xb = X + (size_t)b * Cin * N;
    for (int k0 = kBase; k0 < kBase + chunk; k0 += BK) {
        for (int t = tid; t < TO * BK; t += 256) {
            int o = t / BK, kk = t % BK;
            Ws[kk][o] = W[(size_t)(oBase + o) * Cin + k0 + kk];
        }
        for (int t = tid; t < BK * TN; t += 256) {
            int kk = t / TN, nnn = t % TN;
            Xs[kk][nnn] = Xb[(size_t)(k0 + kk) * N + nBase + nnn];
        }
        __syncthreads();
#pragma unroll
        for (int kk = 0; kk < BK; ++kk) {
            float w0 = Ws[kk][ty * 2 + 0];
            float w1 = Ws[kk][ty * 2 + 1];
            float4 xv = *reinterpret_cast<const float4*>(&Xs[kk][tx * 4]);
            acc[0][0] = fmaf(w0, xv.x, acc[0][0]);
            acc[0][1] = fmaf(w0, xv.y, acc[0][1]);
            acc[0][2] = fmaf(w0, xv.z, acc[0][2]);
            acc[0][3] = fmaf(w0, xv.w, acc[0][3]);
            acc[1][0] = fmaf(w1, xv.x, acc[1][0]);
            acc[1][1] = fmaf(w1, xv.y, acc[1][1]);
            acc[1][2] = fmaf(w1, xv.z, acc[1][2]);
            acc[1][3] = fmaf(w1, xv.w, acc[1][3]);
        }
        __syncthreads();
    }
#pragma unroll
    for (int r = 0; r < 2; ++r) {
        int o = oBase + ty * 2 + r;
        float4 st;
        if (PARTIAL) {
            st.x = acc[r][0]; st.y = acc[r][1]; st.z = acc[r][2]; st.w = acc[r][3];
            *reinterpret_cast<float4*>(&Y[((size_t)zb * Cout + o) * N + nBase + tx * 4]) = st;
        } else {
            float gg = g[o], bb = bv[o];
            st.x = fmaxf(fmaf(acc[r][0], gg, bb), 0.0f);
            st.y = fmaxf(fmaf(acc[r][1], gg, bb), 0.0f);
            st.z = fmaxf(fmaf(acc[r][2], gg, bb), 0.0f);
            st.w = fmaxf(fmaf(acc[r][3], gg, bb), 0.0f);
            *reinterpret_cast<float4*>(&Y[((size_t)b * Cout + o) * N + nBase + tx * 4]) = st;
        }
    }
}

__global__ void reduce_bn_relu_kernel(const float* __restrict__ part,
                                      const float* __restrict__ g,
                                      const float* __restrict__ bv,
                                      float* __restrict__ Y,
                                      int Cout, int N, int total4, int nsplit, int stride4) {
    int t = blockIdx.x * blockDim.x + threadIdx.x;
    if (t >= total4) return;
    const float4* p4 = reinterpret_cast<const float4*>(part);
    float4 a = p4[t];
    for (int s = 1; s < nsplit; ++s) {
        float4 v = p4[t + (size_t)s * stride4];
        a.x += v.x; a.y += v.y; a.z += v.z; a.w += v.w;
    }
    int o = ((t * 4) / N) % Cout;
    float gg = g[o], bb = bv[o];
    float4 st;
    st.x = fmaxf(fmaf(a.x, gg, bb), 0.0f);
    st.y = fmaxf(fmaf(a.y, gg, bb), 0.0f);
    st.z = fmaxf(fmaf(a.z, gg, bb), 0.0f);
    st.w = fmaxf(fmaf(a.w, gg, bb), 0.0f);
    reinterpret_cast<float4*>(Y)[t] = st;
}

extern "C" void kernel_launch(void* const* d_in, const int* in_sizes, int n_in,
                              void* d_out, int out_size, void* d_ws, size_t ws_size,
                              hipStream_t stream) {
    const int B = 8;
    const int Ns[5]  = {8192, 2048, 512, 128, 32};
    const int CHs[5] = {32, 64, 128, 256, 512};

    const float* p[5];
    const float* f[5];
    for (int i = 0; i < 5; ++i) {
        p[i] = (const float*)d_in[2 * i];
        f[i] = (const float*)d_in[2 * i + 1];
    }

    int N1s[4], N2s[4], C1s[4], C2s[4];
    for (int s = 0; s < 4; ++s) {
        int lvl = 3 - s;
        N1s[s] = Ns[lvl]; N2s[s] = Ns[lvl + 1];
        C1s[s] = CHs[lvl];
        C2s[s] = (s == 0) ? CHs[4] : CHs[lvl + 1];
    }
    const int nchunks[4] = {1, 4, 8, 8};
    int chunks[4], nbxs[4];
    for (int s = 0; s < 4; ++s) {
        chunks[s] = N2s[s] / nchunks[s];
        nbxs[s] = (N1s[s] + 255) / 256;
    }

    // ---- workspace layout (floats) ----
    float* ws = (float*)d_ws;
    int*   knn_idx = (int*)ws;                       // 262144
    float* knn_w   = ws + 262144;                    // 262144
    float* part_d  = ws + 524288;                    // 2018304
    int*   part_i  = (int*)(ws + 524288 + 2018304);  // 2018304
    float* bufA    = ws + 524288;                    // 2097152 (after merge)
    float* gpart   = ws + 524288 + 2097152;          // 2097152
    float* out0    = ws + 4718592;                   // 262144
    float* out1    = ws + 4980736;                   // 524288
    float* out2    = ws + 5505024;                   // 1048576
    float4* packed = (float4*)(ws + 6553600);        // 21760 float4
    float* outs[4] = {out0, out1, out2, (float*)d_out};

    int idxOff[4], pOff[4], pkOff[4];
    {
        int a = 0, q = 0, k = 0;
        for (int s = 0; s < 4; ++s) {
            idxOff[s] = a; a += B * N1s[s] * 3;
            pOff[s] = q;  q += B * N1s[s] * nchunks[s] * 3;
            pkOff[s] = k; k += B * N2s[s];
        }
    }

    // ---- pack sparse coords ----
    PackAll PK;
    int cum = 0, cArr[4];
    for (int s = 0; s < 4; ++s) {
        PK.src[s] = p[4 - s];
        PK.dst[s] = packed + pkOff[s];
        cArr[s] = cum;
        cum += B * N2s[s];
    }
    PK.c1 = cArr[1]; PK.c2 = cArr[2]; PK.c3 = cArr[3];
    pack_kernel<<<(cum + 255) / 256, 256, 0, stream>>>(PK, cum);

    // ---- stage-3 kNN: Q=4 ----
    {
        dim3 qg(N1s[3] / 1024, B, nchunks[3]);   // (8,8,8)
        knn_s3_kernel<<<qg, 256, 0, stream>>>(p[0], packed + pkOff[3],
                                              part_d + pOff[3], part_i + pOff[3],
                                              N1s[3], N2s[3], nchunks[3]);
    }

    // ---- stages 0..2 kNN ----
    KnnAll3 KP;
    int blk = 0, bsArr[3];
    for (int s = 0; s < 3; ++s) {
        KP.p1[s] = p[3 - s];
        KP.c4[s] = packed + pkOff[s];
        KP.pd[s] = part_d + pOff[s]; KP.pi[s] = part_i + pOff[s];
        KP.N1[s] = N1s[s]; KP.N2[s] = N2s[s];
        KP.chunk[s] = chunks[s]; KP.nchunk[s] = nchunks[s]; KP.nbx[s] = nbxs[s];
        bsArr[s] = blk;
        blk += nbxs[s] * B * nchunks[s];
    }
    KP.bs1 = bsArr[1]; KP.bs2 = bsArr[2];
    knn_small_kernel<<<blk, 256, 0, stream>>>(KP);

    // ---- merge ----
    MergeAll4 MP;
    int tt = 0, tsArr[4];
    for (int s = 0; s < 4; ++s) {
        MP.pd[s] = part_d + pOff[s]; MP.pi[s] = part_i + pOff[s];
        MP.idx[s] = knn_idx + idxOff[s]; MP.w[s] = knn_w + idxOff[s];
        MP.nchunk[s] = nchunks[s];
        tsArr[s] = tt;
        tt += B * N1s[s];
    }
    MP.ts1 = tsArr[1]; MP.ts2 = tsArr[2]; MP.ts3 = tsArr[3];
    knn_merge_all_kernel<<<(tt + 255) / 256, 256, 0, stream>>>(MP, tt);

    // split-K factors (r5-proven)
    const int nsA[4] = {6, 3, 2, 1};
    const int nsB[4] = {4, 2, 1, 1};

    for (int s = 0; s < 4; ++s) {
        int N1 = N1s[s], N2 = N2s[s];
        int C1 = C1s[s], C2 = C2s[s];
        int Cin = C1 + C2, Cout = C1;
        const float* x2 = (s == 0) ? f[4] : outs[s - 1];
        const float* wa = (const float*)d_in[10 + s * 6 + 0];
        const float* ga = (const float*)d_in[10 + s * 6 + 1];
        const float* ba = (const float*)d_in[10 + s * 6 + 2];
        const float* wb = (const float*)d_in[10 + s * 6 + 3];
        const float* gb = (const float*)d_in[10 + s * 6 + 4];
        const float* bb = (const float*)d_in[10 + s * 6 + 5];
        const int* idxS = knn_idx + idxOff[s];
        const float* wSb = knn_w + idxOff[s];

        {
            int nsplit = nsA[s];
            int chunk = Cin / nsplit;
            dim3 grid(N1 / TN, Cout / TO, B * nsplit);
            if (nsplit == 1) {
                conv_a_fused_kernel<false><<<grid, 256, 0, stream>>>(
                    f[3 - s], x2, idxS, wSb, wa, ga, ba, bufA, C1, C2, N1, N2, Cout, chunk);
            } else {
                conv_a_fused_kernel<true><<<grid, 256, 0, stream>>>(
                    f[3 - s], x2, idxS, wSb, wa, ga, ba, gpart, C1, C2, N1, N2, Cout, chunk);
                int total4 = B * Cout * N1 / 4;
                reduce_bn_relu_kernel<<<(total4 + 255) / 256, 256, 0, stream>>>(
                    gpart, ga, ba, bufA, Cout, N1, total4, nsplit, total4);
            }
        }
        {
            int nsplit = nsB[s];
            int chunk = Cout / nsplit;
            dim3 grid(N1 / TN, Cout / TO, B * nsplit);
            if (nsplit == 1) {
                conv_gemm_kernel<false><<<grid, 256, 0, stream>>>(
                    bufA, wb, gb, bb, outs[s], Cout, Cout, N1, chunk);
            } else {
                conv_gemm_kernel<true><<<grid, 256, 0, stream>>>(
                    bufA, wb, gb, bb, gpart, Cout, Cout, N1, chunk);
                int total4 = B * Cout * N1 / 4;
                reduce_bn_relu_kernel<<<(total4 + 255) / 256, 256, 0, stream>>>(
                    gpart, gb, bb, outs[s], Cout, N1, total4, nsplit, total4);
            }
        }
    }
}

// Round 10
// 242.250 us; speedup vs baseline: 1.3331x; 1.3331x over previous
//
#include <hip/hip_runtime.h>

#define KNN_INF 3.0e38f

// ================== kNN: r5-proven (all 4 stages, LDS-staged, branchy) ==================
struct KnnAll {
    const float* p1[4]; const float* p2[4];
    float* pd[4]; int* pi[4];
    int N1[4], N2[4], chunk[4], nchunk[4], nbx[4];
    int bs1, bs2, bs3;
};

__global__ void knn_all_kernel(KnnAll P) {
    __shared__ float4 sm4[256];
    int bid = blockIdx.x;
    int s = (bid >= P.bs1) + (bid >= P.bs2) + (bid >= P.bs3);
    int start = (s == 0) ? 0 : (s == 1) ? P.bs1 : (s == 2) ? P.bs2 : P.bs3;
    int local = bid - start;
    int nbx = P.nbx[s];
    int bx = local % nbx;
    int rest = local / nbx;
    int b = rest & 7;          // B == 8
    int z = rest >> 3;
    int N1 = P.N1[s], N2 = P.N2[s], chunk = P.chunk[s], nchunk = P.nchunk[s];
    int m0 = z * chunk;
    const float* p2b = P.p2[s] + ((size_t)b * N2 + m0) * 3;
    for (int m = threadIdx.x; m < chunk; m += blockDim.x) {
        float x = p2b[m * 3 + 0], y = p2b[m * 3 + 1], zz = p2b[m * 3 + 2];
        sm4[m] = make_float4(x, y, zz, x * x + y * y + zz * zz);
    }
    __syncthreads();
    int n = bx * blockDim.x + threadIdx.x;
    if (n >= N1) return;
    const float* p1b = P.p1[s] + ((size_t)b * N1 + n) * 3;
    float px = p1b[0], py = p1b[1], pz = p1b[2];
    float s1 = px * px + py * py + pz * pz;
    float d0 = KNN_INF, d1 = KNN_INF, d2 = KNN_INF;
    int i0 = 0, i1 = 0, i2 = 0;
    for (int m = 0; m < chunk; ++m) {
        float4 q = sm4[m];
        float dot = px * q.x + py * q.y + pz * q.z;
        float d = fmaf(-2.0f, dot, s1 + q.w);
        if (d < d2) {
            if (d < d1) {
                d2 = d1; i2 = i1;
                if (d < d0) { d1 = d0; i1 = i0; d0 = d; i0 = m; }
                else        { d1 = d;  i1 = m; }
            } else { d2 = d; i2 = m; }
        }
    }
    size_t base = (((size_t)b * N1 + n) * nchunk + z) * 3;
    float* pd = P.pd[s]; int* pi = P.pi[s];
    pd[base + 0] = d0; pd[base + 1] = d1; pd[base + 2] = d2;
    pi[base + 0] = m0 + i0; pi[base + 1] = m0 + i1; pi[base + 2] = m0 + i2;
}

struct MergeAll {
    const float* pd[4]; const int* pi[4];
    int* idx[4]; float* w[4];
    int nchunk[4];
    int ts1, ts2, ts3;
};

__global__ void knn_merge_all_kernel(MergeAll P, int total) {
    int t = blockIdx.x * blockDim.x + threadIdx.x;
    if (t >= total) return;
    int s = (t >= P.ts1) + (t >= P.ts2) + (t >= P.ts3);
    int start = (s == 0) ? 0 : (s == 1) ? P.ts1 : (s == 2) ? P.ts2 : P.ts3;
    int lt = t - start;
    int nchunk = P.nchunk[s];
    float d0 = KNN_INF, d1 = KNN_INF, d2 = KNN_INF;
    int i0 = 0, i1 = 0, i2 = 0;
    const float* pd = P.pd[s]; const int* pi = P.pi[s];
    size_t base = (size_t)lt * nchunk * 3;
    for (int c = 0; c < nchunk * 3; ++c) {
        float d = pd[base + c];
        int   i = pi[base + c];
        if (d < d2) {
            if (d < d1) {
                d2 = d1; i2 = i1;
                if (d < d0) { d1 = d0; i1 = i0; d0 = d; i0 = i; }
                else        { d1 = d;  i1 = i; }
            } else { d2 = d; i2 = i; }
        }
    }
    float dd0 = fmaxf(d0, 0.0f), dd1 = fmaxf(d1, 0.0f), dd2 = fmaxf(d2, 0.0f);
    float w0 = 1.0f / (dd0 + 1e-8f);
    float w1 = 1.0f / (dd1 + 1e-8f);
    float w2 = 1.0f / (dd2 + 1e-8f);
    float wsum = w0 + w1 + w2;
    w0 /= wsum; w1 /= wsum; w2 /= wsum;
    size_t ob = (size_t)lt * 3;
    P.idx[s][ob + 0] = i0; P.idx[s][ob + 1] = i1; P.idx[s][ob + 2] = i2;
    P.w[s][ob + 0] = w0; P.w[s][ob + 1] = w1; P.w[s][ob + 2] = w2;
}

// ================== conv kernels ==================
#define TO 32
#define TN 64
#define BK 16

// ---- r5 conv_a (gather-fused), split-K capable: stages 0,1 ----
template<bool PARTIAL>
__global__ __launch_bounds__(256) void conv_a_fused_kernel(
    const float* __restrict__ f1, const float* __restrict__ x2,
    const int* __restrict__ idxS, const float* __restrict__ wS,
    const float* __restrict__ W, const float* __restrict__ g, const float* __restrict__ bv,
    float* __restrict__ Y,
    int C1, int C2, int N, int N2, int Cout, int chunk) {
    __shared__ float Ws[BK][TO];
    __shared__ float Xs[BK][TN];
    int Cin = C1 + C2;
    int zb = blockIdx.z;
    int b = zb & 7;
    int split = zb >> 3;
    int kBase = split * chunk;
    int oBase = blockIdx.y * TO;
    int nBase = blockIdx.x * TN;
    int tid = threadIdx.x;
    int tx = tid & 15;
    int ty = tid >> 4;
    int nn = tid & 63;
    int kk0 = tid >> 6;
    int n = nBase + nn;
    size_t gb = ((size_t)b * N + n) * 3;
    int j0 = idxS[gb + 0], j1 = idxS[gb + 1], j2 = idxS[gb + 2];
    float w0g = wS[gb + 0], w1g = wS[gb + 1], w2g = wS[gb + 2];
    const float* f1b = f1 + (size_t)b * C1 * N;
    const float* x2b = x2 + (size_t)b * C2 * N2;
    float acc[2][4] = {{0.f, 0.f, 0.f, 0.f}, {0.f, 0.f, 0.f, 0.f}};
    for (int k0 = kBase; k0 < kBase + chunk; k0 += BK) {
        for (int t = tid; t < TO * BK; t += 256) {
            int o = t / BK, kk = t % BK;
            Ws[kk][o] = W[(size_t)(oBase + o) * Cin + k0 + kk];
        }
#pragma unroll
        for (int i = 0; i < 4; ++i) {
            int kk = kk0 + i * 4;
            int k = k0 + kk;
            float v;
            if (k < C1) {
                v = f1b[(size_t)k * N + n];
            } else {
                const float* r = x2b + (size_t)(k - C1) * N2;
                v = r[j0] * w0g + r[j1] * w1g + r[j2] * w2g;
            }
            Xs[kk][nn] = v;
        }
        __syncthreads();
#pragma unroll
        for (int kk = 0; kk < BK; ++kk) {
            float w0 = Ws[kk][ty * 2 + 0];
            float w1 = Ws[kk][ty * 2 + 1];
            float4 xv = *reinterpret_cast<const float4*>(&Xs[kk][tx * 4]);
            acc[0][0] = fmaf(w0, xv.x, acc[0][0]);
            acc[0][1] = fmaf(w0, xv.y, acc[0][1]);
            acc[0][2] = fmaf(w0, xv.z, acc[0][2]);
            acc[0][3] = fmaf(w0, xv.w, acc[0][3]);
            acc[1][0] = fmaf(w1, xv.x, acc[1][0]);
            acc[1][1] = fmaf(w1, xv.y, acc[1][1]);
            acc[1][2] = fmaf(w1, xv.z, acc[1][2]);
            acc[1][3] = fmaf(w1, xv.w, acc[1][3]);
        }
        __syncthreads();
    }
#pragma unroll
    for (int r = 0; r < 2; ++r) {
        int o = oBase + ty * 2 + r;
        float4 st;
        if (PARTIAL) {
            st.x = acc[r][0]; st.y = acc[r][1]; st.z = acc[r][2]; st.w = acc[r][3];
            *reinterpret_cast<float4*>(&Y[((size_t)zb * Cout + o) * N + nBase + tx * 4]) = st;
        } else {
            float gg = g[o], bb = bv[o];
            st.x = fmaxf(fmaf(acc[r][0], gg, bb), 0.0f);
            st.y = fmaxf(fmaf(acc[r][1], gg, bb), 0.0f);
            st.z = fmaxf(fmaf(acc[r][2], gg, bb), 0.0f);
            st.w = fmaxf(fmaf(acc[r][3], gg, bb), 0.0f);
            *reinterpret_cast<float4*>(&Y[((size_t)b * Cout + o) * N + nBase + tx * 4]) = st;
        }
    }
}

// ---- r5 plain conv (split-K capable): stages 0,1 conv_b ----
template<bool PARTIAL>
__global__ __launch_bounds__(256) void conv_gemm_kernel(
    const float* __restrict__ X, const float* __restrict__ W,
    const float* __restrict__ g, const float* __restrict__ bv,
    float* __restrict__ Y, int Cin, int Cout, int N, int chunk) {
    __shared__ float Ws[BK][TO];
    __shared__ float Xs[BK][TN];
    int zb = blockIdx.z;
    int b = zb & 7;
    int split = zb >> 3;
    int kBase = split * chunk;
    int oBase = blockIdx.y * TO;
    int nBase = blockIdx.x * TN;
    int tid = threadIdx.x;
    int tx = tid & 15;
    int ty = tid >> 4;
    float acc[2][4] = {{0.f, 0.f, 0.f, 0.f}, {0.f, 0.f, 0.f, 0.f}};
    const float* Xb = X + (size_t)b * Cin * N;
    for (int k0 = kBase; k0 < kBase + chunk; k0 += BK) {
        for (int t = tid; t < TO * BK; t += 256) {
            int o = t / BK, kk = t % BK;
            Ws[kk][o] = W[(size_t)(oBase + o) * Cin + k0 + kk];
        }
        for (int t = tid; t < BK * TN; t += 256) {
            int kk = t / TN, nnn = t % TN;
            Xs[kk][nnn] = Xb[(size_t)(k0 + kk) * N + nBase + nnn];
        }
        __syncthreads();
#pragma unroll
        for (int kk = 0; kk < BK; ++kk) {
            float w0 = Ws[kk][ty * 2 + 0];
            float w1 = Ws[kk][ty * 2 + 1];
            float4 xv = *reinterpret_cast<const float4*>(&Xs[kk][tx * 4]);
            acc[0][0] = fmaf(w0, xv.x, acc[0][0]);
            acc[0][1] = fmaf(w0, xv.y, acc[0][1]);
            acc[0][2] = fmaf(w0, xv.z, acc[0][2]);
            acc[0][3] = fmaf(w0, xv.w, acc[0][3]);
            acc[1][0] = fmaf(w1, xv.x, acc[1][0]);
            acc[1][1] = fmaf(w1, xv.y, acc[1][1]);
            acc[1][2] = fmaf(w1, xv.z, acc[1][2]);
            acc[1][3] = fmaf(w1, xv.w, acc[1][3]);
        }
        __syncthreads();
    }
#pragma unroll
    for (int r = 0; r < 2; ++r) {
        int o = oBase + ty * 2 + r;
        float4 st;
        if (PARTIAL) {
            st.x = acc[r][0]; st.y = acc[r][1]; st.z = acc[r][2]; st.w = acc[r][3];
            *reinterpret_cast<float4*>(&Y[((size_t)zb * Cout + o) * N + nBase + tx * 4]) = st;
        } else {
            float gg = g[o], bb = bv[o];
            st.x = fmaxf(fmaf(acc[r][0], gg, bb), 0.0f);
            st.y = fmaxf(fmaf(acc[r][1], gg, bb), 0.0f);
            st.z = fmaxf(fmaf(acc[r][2], gg, bb), 0.0f);
            st.w = fmaxf(fmaf(acc[r][3], gg, bb), 0.0f);
            *reinterpret_cast<float4*>(&Y[((size_t)b * Cout + o) * N + nBase + tx * 4]) = st;
        }
    }
}

__global__ void reduce_bn_relu_kernel(const float* __restrict__ part,
                                      const float* __restrict__ g,
                                      const float* __restrict__ bv,
                                      float* __restrict__ Y,
                                      int Cout, int N, int total4, int nsplit, int stride4) {
    int t = blockIdx.x * blockDim.x + threadIdx.x;
    if (t >= total4) return;
    const float4* p4 = reinterpret_cast<const float4*>(part);
    float4 a = p4[t];
    for (int s = 1; s < nsplit; ++s) {
        float4 v = p4[t + (size_t)s * stride4];
        a.x += v.x; a.y += v.y; a.z += v.z; a.w += v.w;
    }
    int o = ((t * 4) / N) % Cout;
    float gg = g[o], bb = bv[o];
    float4 st;
    st.x = fmaxf(fmaf(a.x, gg, bb), 0.0f);
    st.y = fmaxf(fmaf(a.y, gg, bb), 0.0f);
    st.z = fmaxf(fmaf(a.z, gg, bb), 0.0f);
    st.w = fmaxf(fmaf(a.w, gg, bb), 0.0f);
    reinterpret_cast<float4*>(Y)[t] = st;
}

// ---- fused conv_a + conv_b for stages 2,3: full-Cout tile, conv_a -> LDS -> conv_b ----
template<int COUT, int TNF>
__global__ __launch_bounds__(256) void conv_ab_fused_kernel(
    const float* __restrict__ f1, const float* __restrict__ x2,
    const int* __restrict__ idxS, const float* __restrict__ wS,
    const float* __restrict__ Wa, const float* __restrict__ ga, const float* __restrict__ ba,
    const float* __restrict__ Wb, const float* __restrict__ gbv, const float* __restrict__ bbv,
    float* __restrict__ Y,
    int C1, int C2, int N, int N2) {
    constexpr int TX  = TNF / 4;        // threads along n
    constexpr int RPP = 256 / TNF;      // k-rows staged per pass
    __shared__ float Ws_[BK][COUT];
    __shared__ float Xs[BK][TNF];
    __shared__ float Ya[COUT][TNF];
    int Cin = C1 + C2;
    int b = blockIdx.z;
    int nBase = blockIdx.x * TNF;
    int tid = threadIdx.x;
    int tx = tid % TX;
    int ty = tid / TX;                  // 0 .. COUT/2-1
    int nn = tid % TNF;
    int kk0 = tid / TNF;
    int n = nBase + nn;
    size_t gb = ((size_t)b * N + n) * 3;
    int j0 = idxS[gb + 0], j1 = idxS[gb + 1], j2 = idxS[gb + 2];
    float w0g = wS[gb + 0], w1g = wS[gb + 1], w2g = wS[gb + 2];
    const float* f1b = f1 + (size_t)b * C1 * N;
    const float* x2b = x2 + (size_t)b * C2 * N2;
    float acc[2][4] = {{0.f, 0.f, 0.f, 0.f}, {0.f, 0.f, 0.f, 0.f}};
    // ---- conv_a ----
    for (int k0 = 0; k0 < Cin; k0 += BK) {
        for (int t = tid; t < COUT * BK; t += 256) {
            int o = t / BK, kk = t % BK;
            Ws_[kk][o] = Wa[(size_t)o * Cin + k0 + kk];
        }
#pragma unroll
        for (int i = 0; i < BK / RPP; ++i) {
            int kk = kk0 + i * RPP;
            int k = k0 + kk;
            float v;
            if (k < C1) {
                v = f1b[(size_t)k * N + n];
            } else {
                const float* r = x2b + (size_t)(k - C1) * N2;
                v = r[j0] * w0g + r[j1] * w1g + r[j2] * w2g;
            }
            Xs[kk][nn] = v;
        }
        __syncthreads();
#pragma unroll
        for (int kk = 0; kk < BK; ++kk) {
            float w0 = Ws_[kk][ty * 2 + 0];
            float w1 = Ws_[kk][ty * 2 + 1];
            float4 xv = *reinterpret_cast<const float4*>(&Xs[kk][tx * 4]);
            acc[0][0] = fmaf(w0, xv.x, acc[0][0]);
            acc[0][1] = fmaf(w0, xv.y, acc[0][1]);
            acc[0][2] = fmaf(w0, xv.z, acc[0][2]);
            acc[0][3] = fmaf(w0, xv.w, acc[0][3]);
            acc[1][0] = fmaf(w1, xv.x, acc[1][0]);
            acc[1][1] = fmaf(w1, xv.y, acc[1][1]);
            acc[1][2] = fmaf(w1, xv.z, acc[1][2]);
            acc[1][3] = fmaf(w1, xv.w, acc[1][3]);
        }
        __syncthreads();
    }
    // conv_a epilogue -> Ya (LDS)
#pragma unroll
    for (int r = 0; r < 2; ++r) {
        int o = ty * 2 + r;
        float gg = ga[o], bb = ba[o];
        float4 st;
        st.x = fmaxf(fmaf(acc[r][0], gg, bb), 0.0f);
        st.y = fmaxf(fmaf(acc[r][1], gg, bb), 0.0f);
        st.z = fmaxf(fmaf(acc[r][2], gg, bb), 0.0f);
        st.w = fmaxf(fmaf(acc[r][3], gg, bb), 0.0f);
        *reinterpret_cast<float4*>(&Ya[o][tx * 4]) = st;
        acc[r][0] = acc[r][1] = acc[r][2] = acc[r][3] = 0.f;
    }
    // ---- conv_b ----
    for (int k0 = 0; k0 < COUT; k0 += BK) {
        __syncthreads();     // Ya ready (first iter) / previous compute done
        for (int t = tid; t < COUT * BK; t += 256) {
            int o = t / BK, kk = t % BK;
            Ws_[kk][o] = Wb[(size_t)o * COUT + k0 + kk];
        }
        __syncthreads();
#pragma unroll
        for (int kk = 0; kk < BK; ++kk) {
            float w0 = Ws_[kk][ty * 2 + 0];
            float w1 = Ws_[kk][ty * 2 + 1];
            float4 xv = *reinterpret_cast<const float4*>(&Ya[k0 + kk][tx * 4]);
            acc[0][0] = fmaf(w0, xv.x, acc[0][0]);
            acc[0][1] = fmaf(w0, xv.y, acc[0][1]);
            acc[0][2] = fmaf(w0, xv.z, acc[0][2]);
            acc[0][3] = fmaf(w0, xv.w, acc[0][3]);
            acc[1][0] = fmaf(w1, xv.x, acc[1][0]);
            acc[1][1] = fmaf(w1, xv.y, acc[1][1]);
            acc[1][2] = fmaf(w1, xv.z, acc[1][2]);
            acc[1][3] = fmaf(w1, xv.w, acc[1][3]);
        }
    }
#pragma unroll
    for (int r = 0; r < 2; ++r) {
        int o = ty * 2 + r;
        float gg = gbv[o], bb = bbv[o];
        float4 st;
        st.x = fmaxf(fmaf(acc[r][0], gg, bb), 0.0f);
        st.y = fmaxf(fmaf(acc[r][1], gg, bb), 0.0f);
        st.z = fmaxf(fmaf(acc[r][2], gg, bb), 0.0f);
        st.w = fmaxf(fmaf(acc[r][3], gg, bb), 0.0f);
        *reinterpret_cast<float4*>(&Y[((size_t)b * COUT + o) * N + nBase + tx * 4]) = st;
    }
}

extern "C" void kernel_launch(void* const* d_in, const int* in_sizes, int n_in,
                              void* d_out, int out_size, void* d_ws, size_t ws_size,
                              hipStream_t stream) {
    const int B = 8;
    const int Ns[5]  = {8192, 2048, 512, 128, 32};
    const int CHs[5] = {32, 64, 128, 256, 512};

    const float* p[5];
    const float* f[5];
    for (int i = 0; i < 5; ++i) {
        p[i] = (const float*)d_in[2 * i];
        f[i] = (const float*)d_in[2 * i + 1];
    }

    int N1s[4], N2s[4], C1s[4], C2s[4];
    for (int s = 0; s < 4; ++s) {
        int lvl = 3 - s;
        N1s[s] = Ns[lvl]; N2s[s] = Ns[lvl + 1];
        C1s[s] = CHs[lvl];
        C2s[s] = (s == 0) ? CHs[4] : CHs[lvl + 1];
    }
    const int nchunks[4] = {1, 4, 8, 8};
    int chunks[4], nbxs[4];
    for (int s = 0; s < 4; ++s) {
        chunks[s] = N2s[s] / nchunks[s];
        nbxs[s] = (N1s[s] + 255) / 256;
    }

    // ---- workspace layout (floats) — r5-proven ----
    float* ws = (float*)d_ws;
    int*   knn_idx = (int*)ws;                  // 262144
    float* knn_w   = ws + 262144;               // 262144
    float* part_d  = ws + 524288;               // 2018304
    int*   part_i  = (int*)(ws + 2621440);      // 2018304
    float* bufA    = ws + 4718592;              // 2097152 (stages 0,1 only now)
    float* out0    = ws + 6815744;              // 262144
    float* out1    = ws + 7077888;              // 524288
    float* out2    = ws + 7602176;              // 1048576
    float* gpart   = ws + 8650752;              // 1572864 max
    float* outs[4] = {out0, out1, out2, (float*)d_out};

    int idxOff[4], pOff[4];
    {
        int a = 0, q = 0;
        for (int s = 0; s < 4; ++s) {
            idxOff[s] = a; a += B * N1s[s] * 3;
            pOff[s] = q;  q += B * N1s[s] * nchunks[s] * 3;
        }
    }

    // ---- one combined kNN launch for all stages (r5) ----
    KnnAll KP;
    int blk = 0, bsArr[4];
    for (int s = 0; s < 4; ++s) {
        KP.p1[s] = p[3 - s]; KP.p2[s] = p[4 - s];
        KP.pd[s] = part_d + pOff[s]; KP.pi[s] = part_i + pOff[s];
        KP.N1[s] = N1s[s]; KP.N2[s] = N2s[s];
        KP.chunk[s] = chunks[s]; KP.nchunk[s] = nchunks[s]; KP.nbx[s] = nbxs[s];
        bsArr[s] = blk;
        blk += nbxs[s] * B * nchunks[s];
    }
    KP.bs1 = bsArr[1]; KP.bs2 = bsArr[2]; KP.bs3 = bsArr[3];
    knn_all_kernel<<<blk, 256, 0, stream>>>(KP);

    // ---- one combined merge launch (r5) ----
    MergeAll MP;
    int tt = 0, tsArr[4];
    for (int s = 0; s < 4; ++s) {
        MP.pd[s] = part_d + pOff[s]; MP.pi[s] = part_i + pOff[s];
        MP.idx[s] = knn_idx + idxOff[s]; MP.w[s] = knn_w + idxOff[s];
        MP.nchunk[s] = nchunks[s];
        tsArr[s] = tt;
        tt += B * N1s[s];
    }
    MP.ts1 = tsArr[1]; MP.ts2 = tsArr[2]; MP.ts3 = tsArr[3];
    knn_merge_all_kernel<<<(tt + 255) / 256, 256, 0, stream>>>(MP, tt);

    const int nsA[4] = {6, 3, 2, 1};
    const int nsB[4] = {4, 2, 1, 1};

    for (int s = 0; s < 4; ++s) {
        int N1 = N1s[s], N2 = N2s[s];
        int C1 = C1s[s], C2 = C2s[s];
        int Cin = C1 + C2, Cout = C1;
        const float* x2 = (s == 0) ? f[4] : outs[s - 1];
        const float* wa = (const float*)d_in[10 + s * 6 + 0];
        const float* ga = (const float*)d_in[10 + s * 6 + 1];
        const float* ba = (const float*)d_in[10 + s * 6 + 2];
        const float* wb = (const float*)d_in[10 + s * 6 + 3];
        const float* gb = (const float*)d_in[10 + s * 6 + 4];
        const float* bb = (const float*)d_in[10 + s * 6 + 5];
        const int* idxS = knn_idx + idxOff[s];
        const float* wSb = knn_w + idxOff[s];

        if (s == 2) {
            // fused conv_a+conv_b: COUT=64, TN=32
            dim3 grid(N1 / 32, 1, B);
            conv_ab_fused_kernel<64, 32><<<grid, 256, 0, stream>>>(
                f[3 - s], x2, idxS, wSb, wa, ga, ba, wb, gb, bb, outs[s], C1, C2, N1, N2);
            continue;
        }
        if (s == 3) {
            // fused conv_a+conv_b: COUT=32, TN=64
            dim3 grid(N1 / 64, 1, B);
            conv_ab_fused_kernel<32, 64><<<grid, 256, 0, stream>>>(
                f[3 - s], x2, idxS, wSb, wa, ga, ba, wb, gb, bb, outs[s], C1, C2, N1, N2);
            continue;
        }

        // stages 0,1: r5 split-K path
        {
            int nsplit = nsA[s];
            int chunk = Cin / nsplit;
            dim3 grid(N1 / TN, Cout / TO, B * nsplit);
            conv_a_fused_kernel<true><<<grid, 256, 0, stream>>>(
                f[3 - s], x2, idxS, wSb, wa, ga, ba, gpart, C1, C2, N1, N2, Cout, chunk);
            int total4 = B * Cout * N1 / 4;
            reduce_bn_relu_kernel<<<(total4 + 255) / 256, 256, 0, stream>>>(
                gpart, ga, ba, bufA, Cout, N1, total4, nsplit, total4);
        }
        {
            int nsplit = nsB[s];
            int chunk = Cout / nsplit;
            dim3 grid(N1 / TN, Cout / TO, B * nsplit);
            conv_gemm_kernel<true><<<grid, 256, 0, stream>>>(
                bufA, wb, gb, bb, gpart, Cout, Cout, N1, chunk);
            int total4 = B * Cout * N1 / 4;
            reduce_bn_relu_kernel<<<(total4 + 255) / 256, 256, 0, stream>>>(
                gpart, gb, bb, outs[s], Cout, N1, total4, nsplit, total4);
        }
    }
}